// Round 1
// baseline (1742.409 us; speedup 1.0000x reference)
//
#include <hip/hip_runtime.h>

#define T_TOKENS 8192
#define DM 1024
#define DFF 4096
#define NE 8
#define CAP 2560
#define LDA 72  // padded LDS row stride in fp16 (64 + 8 pad -> conflict-free frag reads)

typedef _Float16 f16x8 __attribute__((ext_vector_type(8)));
typedef _Float16 f16x4 __attribute__((ext_vector_type(4)));
typedef float f32x4 __attribute__((ext_vector_type(4)));

// ---------------- Kernel 1: LayerNorm + router (logits, softmax, top-2) ----------------
__global__ __launch_bounds__(256) void ln_router_kernel(
    const float* __restrict__ x, const float* __restrict__ gamma,
    const float* __restrict__ beta, const float* __restrict__ Wr,
    _Float16* __restrict__ xn16, int* __restrict__ slot_e, float* __restrict__ slot_w)
{
    int tok = blockIdx.x;
    int tid = threadIdx.x;
    int lane = tid & 63, wave = tid >> 6;
    const float* xr = x + (size_t)tok * DM + tid * 4;
    float4 xv = *(const float4*)xr;
    float s  = xv.x + xv.y + xv.z + xv.w;
    float ss = xv.x * xv.x + xv.y * xv.y + xv.z * xv.z + xv.w * xv.w;
    __shared__ float redS[4], redQ[4];
    __shared__ float l8s[4][NE];
    __shared__ float stats[2];
    #pragma unroll
    for (int o = 32; o > 0; o >>= 1) { s += __shfl_down(s, o); ss += __shfl_down(ss, o); }
    if (lane == 0) { redS[wave] = s; redQ[wave] = ss; }
    __syncthreads();
    if (tid == 0) {
        float S = redS[0] + redS[1] + redS[2] + redS[3];
        float Q = redQ[0] + redQ[1] + redQ[2] + redQ[3];
        float mu = S * (1.0f / DM);
        float var = Q * (1.0f / DM) - mu * mu;
        stats[0] = mu;
        stats[1] = rsqrtf(var + 1e-5f);
    }
    __syncthreads();
    float mu = stats[0], rstd = stats[1];
    float4 gv = *(const float4*)(gamma + tid * 4);
    float4 bv = *(const float4*)(beta + tid * 4);
    float xn0 = (xv.x - mu) * rstd * gv.x + bv.x;
    float xn1 = (xv.y - mu) * rstd * gv.y + bv.y;
    float xn2 = (xv.z - mu) * rstd * gv.z + bv.z;
    float xn3 = (xv.w - mu) * rstd * gv.w + bv.w;
    f16x4 h4 = { (_Float16)xn0, (_Float16)xn1, (_Float16)xn2, (_Float16)xn3 };
    *(f16x4*)(xn16 + (size_t)tok * DM + tid * 4) = h4;
    float l[NE];
    #pragma unroll
    for (int e = 0; e < NE; e++) {
        float4 wv = *(const float4*)(Wr + e * DM + tid * 4);
        l[e] = xn0 * wv.x + xn1 * wv.y + xn2 * wv.z + xn3 * wv.w;
    }
    #pragma unroll
    for (int e = 0; e < NE; e++) {
        #pragma unroll
        for (int o = 32; o > 0; o >>= 1) l[e] += __shfl_down(l[e], o);
    }
    if (lane == 0) {
        #pragma unroll
        for (int e = 0; e < NE; e++) l8s[wave][e] = l[e];
    }
    __syncthreads();
    if (tid == 0) {
        float lg[NE], ex[NE];
        float m = -1e30f;
        #pragma unroll
        for (int e = 0; e < NE; e++) {
            float v = l8s[0][e] + l8s[1][e] + l8s[2][e] + l8s[3][e];
            v = fminf(fmaxf(v, -10000.0f), 10000.0f);
            lg[e] = v;
            m = fmaxf(m, v);
        }
        float sum = 0.0f;
        #pragma unroll
        for (int e = 0; e < NE; e++) { ex[e] = expf(lg[e] - m); sum += ex[e]; }
        float inv = 1.0f / (sum + 1e-12f);
        int i0 = 0;
        #pragma unroll
        for (int e = 1; e < NE; e++) if (ex[e] > ex[i0]) i0 = e;
        int i1 = (i0 == 0) ? 1 : 0;
        #pragma unroll
        for (int e = 0; e < NE; e++) if (e != i0 && ex[e] > ex[i1]) i1 = e;
        slot_e[2 * tok]     = i0; slot_w[2 * tok]     = ex[i0] * inv;
        slot_e[2 * tok + 1] = i1; slot_w[2 * tok + 1] = ex[i1] * inv;
    }
}

// ------- Kernel 2: stable counting-sort routing: rank-within-expert + capacity drop -------
__global__ __launch_bounds__(1024) void route_build_kernel(
    const int* __restrict__ slot_e, const float* __restrict__ slot_w,
    int* __restrict__ slot_row, int* __restrict__ row_token, float* __restrict__ row_w,
    int* __restrict__ n_rows)
{
    __shared__ int hist[1024][NE];
    int t = threadIdx.x;
    int cnt[NE];
    #pragma unroll
    for (int e = 0; e < NE; e++) cnt[e] = 0;
    int se[16];
    #pragma unroll
    for (int i = 0; i < 16; i++) { se[i] = slot_e[t * 16 + i]; cnt[se[i]]++; }
    #pragma unroll
    for (int e = 0; e < NE; e++) hist[t][e] = cnt[e];
    __syncthreads();
    for (int off = 1; off < 1024; off <<= 1) {
        int v[NE];
        bool has = (t >= off);
        if (has) {
            #pragma unroll
            for (int e = 0; e < NE; e++) v[e] = hist[t - off][e];
        }
        __syncthreads();
        if (has) {
            #pragma unroll
            for (int e = 0; e < NE; e++) hist[t][e] += v[e];
        }
        __syncthreads();
    }
    int run[NE];
    #pragma unroll
    for (int e = 0; e < NE; e++) run[e] = hist[t][e] - cnt[e];  // exclusive prefix
    if (t < NE) n_rows[t] = min(hist[1023][t], CAP);
    for (int i = 0; i < 16; i++) {
        int sidx = t * 16 + i;
        int e = se[i];
        int rnk = run[e]++;
        if (rnk < CAP) {
            int dest = e * CAP + rnk;
            slot_row[sidx] = dest;
            row_token[dest] = sidx >> 1;
            row_w[dest] = slot_w[sidx];
        } else {
            slot_row[sidx] = -1;
        }
    }
}

// ---------------- Kernel 3: gather xn rows into per-expert buffer ----------------
__global__ __launch_bounds__(128) void gather_kernel(
    const _Float16* __restrict__ xn16, const int* __restrict__ slot_row,
    _Float16* __restrict__ buf)
{
    int s = blockIdx.x;
    int dest = slot_row[s];
    if (dest < 0) return;
    int tok = s >> 1;
    int t = threadIdx.x;
    *(f16x8*)(buf + (size_t)dest * DM + t * 8) =
        *(const f16x8*)(xn16 + (size_t)tok * DM + t * 8);
}

// ------- Kernel 4: GEMM1 (buf @ W12^T) with dual g/u accumulators + fused SiLU*u -------
// block tile: 128 rows x 128 h-cols (g uses W12 rows [c0,c0+128), u uses [4096+c0, ...))
__global__ __launch_bounds__(256, 2) void gemm1_kernel(
    const _Float16* __restrict__ buf, const float* __restrict__ W12,
    const int* __restrict__ n_rows, _Float16* __restrict__ H)
{
    int e = blockIdx.z;
    int m0 = blockIdx.y * 128;
    int c0 = blockIdx.x * 128;
    int ne = n_rows[e];
    if (m0 >= ne) return;
    const _Float16* A = buf + ((size_t)e * CAP + m0) * DM;
    const float* W = W12 + (size_t)e * (2 * DFF) * DM;
    __shared__ _Float16 Al[128 * LDA];
    __shared__ _Float16 Bl[256 * LDA];
    int tid = threadIdx.x;
    int lane = tid & 63, wave = tid >> 6;
    int r = lane & 15, q = lane >> 4;
    int wm = (wave & 1) * 64, wn = (wave >> 1) * 64;
    f32x4 accg[4][4] = {};
    f32x4 accu[4][4] = {};
    for (int k0 = 0; k0 < DM; k0 += 64) {
        // stage A: 128 rows x 64 fp16
        #pragma unroll
        for (int v = 0; v < 4; v++) {
            int ci = tid + v * 256;
            int row = ci >> 3, ch = ci & 7;
            f16x8 d = *(const f16x8*)(A + (size_t)row * DM + k0 + ch * 8);
            *(f16x8*)(&Al[row * LDA + ch * 8]) = d;
        }
        // stage B: 256 rows (128 g + 128 u) x 64, fp32 -> fp16 convert
        #pragma unroll
        for (int v = 0; v < 8; v++) {
            int ci = tid + v * 256;
            int row = ci >> 3, ch = ci & 7;
            int frow = (row < 128) ? (c0 + row) : (DFF + c0 + row - 128);
            const float* src = W + (size_t)frow * DM + k0 + ch * 8;
            float4 s0 = *(const float4*)(src);
            float4 s1 = *(const float4*)(src + 4);
            f16x8 d = { (_Float16)s0.x, (_Float16)s0.y, (_Float16)s0.z, (_Float16)s0.w,
                        (_Float16)s1.x, (_Float16)s1.y, (_Float16)s1.z, (_Float16)s1.w };
            *(f16x8*)(&Bl[row * LDA + ch * 8]) = d;
        }
        __syncthreads();
        #pragma unroll
        for (int kf = 0; kf < 2; kf++) {
            f16x8 a[4], bg[4], bu[4];
            #pragma unroll
            for (int i = 0; i < 4; i++)
                a[i] = *(const f16x8*)(&Al[(wm + i * 16 + r) * LDA + kf * 32 + q * 8]);
            #pragma unroll
            for (int j = 0; j < 4; j++) {
                bg[j] = *(const f16x8*)(&Bl[(wn + j * 16 + r) * LDA + kf * 32 + q * 8]);
                bu[j] = *(const f16x8*)(&Bl[(128 + wn + j * 16 + r) * LDA + kf * 32 + q * 8]);
            }
            #pragma unroll
            for (int i = 0; i < 4; i++) {
                #pragma unroll
                for (int j = 0; j < 4; j++) {
                    accg[i][j] = __builtin_amdgcn_mfma_f32_16x16x32_f16(a[i], bg[j], accg[i][j], 0, 0, 0);
                    accu[i][j] = __builtin_amdgcn_mfma_f32_16x16x32_f16(a[i], bu[j], accu[i][j], 0, 0, 0);
                }
            }
        }
        __syncthreads();
    }
    // epilogue: h = silu(g) * u, store fp16
    #pragma unroll
    for (int i = 0; i < 4; i++) {
        #pragma unroll
        for (int j = 0; j < 4; j++) {
            #pragma unroll
            for (int g = 0; g < 4; g++) {
                int row = wm + i * 16 + q * 4 + g;
                int col = wn + j * 16 + r;
                float gv = accg[i][j][g], uv = accu[i][j][g];
                float h = gv / (1.0f + __expf(-gv)) * uv;
                H[((size_t)(e * CAP + m0 + row)) * DFF + c0 + col] = (_Float16)h;
            }
        }
    }
}

// ------- Kernel 5: GEMM2 (h @ W3^T) with fused weighted atomic scatter-combine -------
__global__ __launch_bounds__(256, 2) void gemm2_kernel(
    const _Float16* __restrict__ H, const float* __restrict__ W3,
    const int* __restrict__ n_rows, const int* __restrict__ row_token,
    const float* __restrict__ row_w, float* __restrict__ out)
{
    int e = blockIdx.z;
    int m0 = blockIdx.y * 128;
    int c0 = blockIdx.x * 128;
    int ne = n_rows[e];
    if (m0 >= ne) return;
    const _Float16* A = H + ((size_t)(e * CAP + m0)) * DFF;
    const float* W = W3 + (size_t)e * DM * DFF;
    __shared__ _Float16 Al[128 * LDA];
    __shared__ _Float16 Bl[128 * LDA];
    int tid = threadIdx.x;
    int lane = tid & 63, wave = tid >> 6;
    int r = lane & 15, q = lane >> 4;
    int wm = (wave & 1) * 64, wn = (wave >> 1) * 64;
    f32x4 acc[4][4] = {};
    for (int k0 = 0; k0 < DFF; k0 += 64) {
        #pragma unroll
        for (int v = 0; v < 4; v++) {
            int ci = tid + v * 256;
            int row = ci >> 3, ch = ci & 7;
            f16x8 d = *(const f16x8*)(A + (size_t)row * DFF + k0 + ch * 8);
            *(f16x8*)(&Al[row * LDA + ch * 8]) = d;
        }
        #pragma unroll
        for (int v = 0; v < 4; v++) {
            int ci = tid + v * 256;
            int row = ci >> 3, ch = ci & 7;
            const float* src = W + (size_t)(c0 + row) * DFF + k0 + ch * 8;
            float4 s0 = *(const float4*)(src);
            float4 s1 = *(const float4*)(src + 4);
            f16x8 d = { (_Float16)s0.x, (_Float16)s0.y, (_Float16)s0.z, (_Float16)s0.w,
                        (_Float16)s1.x, (_Float16)s1.y, (_Float16)s1.z, (_Float16)s1.w };
            *(f16x8*)(&Bl[row * LDA + ch * 8]) = d;
        }
        __syncthreads();
        #pragma unroll
        for (int kf = 0; kf < 2; kf++) {
            f16x8 a[4], b[4];
            #pragma unroll
            for (int i = 0; i < 4; i++)
                a[i] = *(const f16x8*)(&Al[(wm + i * 16 + r) * LDA + kf * 32 + q * 8]);
            #pragma unroll
            for (int j = 0; j < 4; j++)
                b[j] = *(const f16x8*)(&Bl[(wn + j * 16 + r) * LDA + kf * 32 + q * 8]);
            #pragma unroll
            for (int i = 0; i < 4; i++) {
                #pragma unroll
                for (int j = 0; j < 4; j++)
                    acc[i][j] = __builtin_amdgcn_mfma_f32_16x16x32_f16(a[i], b[j], acc[i][j], 0, 0, 0);
            }
        }
        __syncthreads();
    }
    // epilogue: out[token] += w * y  (each out element touched by <= 2 slots)
    #pragma unroll
    for (int i = 0; i < 4; i++) {
        #pragma unroll
        for (int g = 0; g < 4; g++) {
            int m = m0 + wm + i * 16 + q * 4 + g;
            if (m < ne) {
                int dest = e * CAP + m;
                int tok = row_token[dest];
                float w = row_w[dest];
                #pragma unroll
                for (int j = 0; j < 4; j++) {
                    int col = c0 + wn + j * 16 + r;
                    atomicAdd(out + (size_t)tok * DM + col, w * acc[i][j][g]);
                }
            }
        }
    }
}

extern "C" void kernel_launch(void* const* d_in, const int* in_sizes, int n_in,
                              void* d_out, int out_size, void* d_ws, size_t ws_size,
                              hipStream_t stream) {
    const float* x     = (const float*)d_in[0];
    const float* gamma = (const float*)d_in[1];
    const float* beta  = (const float*)d_in[2];
    const float* Wr    = (const float*)d_in[3];
    const float* W12   = (const float*)d_in[4];
    const float* W3    = (const float*)d_in[5];
    float* out = (float*)d_out;
    char* ws = (char*)d_ws;

    _Float16* xn16    = (_Float16*)(ws);                 // 16,777,216 B
    _Float16* buf     = (_Float16*)(ws + 16777216);      // 41,943,040 B
    _Float16* H       = (_Float16*)(ws + 58720256);      // 167,772,160 B
    int*      slot_e  = (int*)(ws + 226492416);          // 65,536 B
    float*    slot_w  = (float*)(ws + 226557952);        // 65,536 B
    int*      slot_row= (int*)(ws + 226623488);          // 65,536 B
    int*      row_tok = (int*)(ws + 226689024);          // 81,920 B
    float*    row_w   = (float*)(ws + 226770944);        // 81,920 B
    int*      n_rows  = (int*)(ws + 226852864);          // 32 B

    hipMemsetAsync(d_out, 0, (size_t)out_size * sizeof(float), stream);

    hipLaunchKernelGGL(ln_router_kernel, dim3(T_TOKENS), dim3(256), 0, stream,
                       x, gamma, beta, Wr, xn16, slot_e, slot_w);
    hipLaunchKernelGGL(route_build_kernel, dim3(1), dim3(1024), 0, stream,
                       slot_e, slot_w, slot_row, row_tok, row_w, n_rows);
    hipLaunchKernelGGL(gather_kernel, dim3(2 * T_TOKENS), dim3(128), 0, stream,
                       xn16, slot_row, buf);
    hipLaunchKernelGGL(gemm1_kernel, dim3(32, 20, NE), dim3(256), 0, stream,
                       buf, W12, n_rows, H);
    hipLaunchKernelGGL(gemm2_kernel, dim3(8, 20, NE), dim3(256), 0, stream,
                       H, W3, n_rows, row_tok, row_w, out);
}

// Round 2
// 1066.751 us; speedup vs baseline: 1.6334x; 1.6334x over previous
//
#include <hip/hip_runtime.h>

#define T_TOKENS 8192
#define DM 1024
#define DFF 4096
#define NE 8
#define CAP 2560

typedef _Float16 f16x8 __attribute__((ext_vector_type(8)));
typedef _Float16 f16x4 __attribute__((ext_vector_type(4)));
typedef float f32x4 __attribute__((ext_vector_type(4)));

__device__ __forceinline__ void async16(const _Float16* g, _Float16* l) {
    __builtin_amdgcn_global_load_lds(
        (const __attribute__((address_space(1))) void*)g,
        (__attribute__((address_space(3))) void*)l, 16, 0, 0);
}

// ---------------- Kernel 0: fp32 -> fp16 weight convert ----------------
__global__ __launch_bounds__(256) void convert_kernel(
    const float* __restrict__ src, _Float16* __restrict__ dst, int n4)
{
    int i = blockIdx.x * blockDim.x + threadIdx.x;
    int stride = gridDim.x * blockDim.x;
    for (; i < n4; i += stride) {
        float4 v = ((const float4*)src)[i];
        f16x4 h = { (_Float16)v.x, (_Float16)v.y, (_Float16)v.z, (_Float16)v.w };
        ((f16x4*)dst)[i] = h;
    }
}

// ---------------- Kernel 1: LayerNorm + router (logits, softmax, top-2) ----------------
__global__ __launch_bounds__(256) void ln_router_kernel(
    const float* __restrict__ x, const float* __restrict__ gamma,
    const float* __restrict__ beta, const float* __restrict__ Wr,
    _Float16* __restrict__ xn16, int* __restrict__ slot_e, float* __restrict__ slot_w)
{
    int tok = blockIdx.x;
    int tid = threadIdx.x;
    int lane = tid & 63, wave = tid >> 6;
    const float* xr = x + (size_t)tok * DM + tid * 4;
    float4 xv = *(const float4*)xr;
    float s  = xv.x + xv.y + xv.z + xv.w;
    float ss = xv.x * xv.x + xv.y * xv.y + xv.z * xv.z + xv.w * xv.w;
    __shared__ float redS[4], redQ[4];
    __shared__ float l8s[4][NE];
    __shared__ float stats[2];
    #pragma unroll
    for (int o = 32; o > 0; o >>= 1) { s += __shfl_down(s, o); ss += __shfl_down(ss, o); }
    if (lane == 0) { redS[wave] = s; redQ[wave] = ss; }
    __syncthreads();
    if (tid == 0) {
        float S = redS[0] + redS[1] + redS[2] + redS[3];
        float Q = redQ[0] + redQ[1] + redQ[2] + redQ[3];
        float mu = S * (1.0f / DM);
        float var = Q * (1.0f / DM) - mu * mu;
        stats[0] = mu;
        stats[1] = rsqrtf(var + 1e-5f);
    }
    __syncthreads();
    float mu = stats[0], rstd = stats[1];
    float4 gv = *(const float4*)(gamma + tid * 4);
    float4 bv = *(const float4*)(beta + tid * 4);
    float xn0 = (xv.x - mu) * rstd * gv.x + bv.x;
    float xn1 = (xv.y - mu) * rstd * gv.y + bv.y;
    float xn2 = (xv.z - mu) * rstd * gv.z + bv.z;
    float xn3 = (xv.w - mu) * rstd * gv.w + bv.w;
    f16x4 h4 = { (_Float16)xn0, (_Float16)xn1, (_Float16)xn2, (_Float16)xn3 };
    *(f16x4*)(xn16 + (size_t)tok * DM + tid * 4) = h4;
    float l[NE];
    #pragma unroll
    for (int e = 0; e < NE; e++) {
        float4 wv = *(const float4*)(Wr + e * DM + tid * 4);
        l[e] = xn0 * wv.x + xn1 * wv.y + xn2 * wv.z + xn3 * wv.w;
    }
    #pragma unroll
    for (int e = 0; e < NE; e++) {
        #pragma unroll
        for (int o = 32; o > 0; o >>= 1) l[e] += __shfl_down(l[e], o);
    }
    if (lane == 0) {
        #pragma unroll
        for (int e = 0; e < NE; e++) l8s[wave][e] = l[e];
    }
    __syncthreads();
    if (tid == 0) {
        float lg[NE], ex[NE];
        float m = -1e30f;
        #pragma unroll
        for (int e = 0; e < NE; e++) {
            float v = l8s[0][e] + l8s[1][e] + l8s[2][e] + l8s[3][e];
            v = fminf(fmaxf(v, -10000.0f), 10000.0f);
            lg[e] = v;
            m = fmaxf(m, v);
        }
        float sum = 0.0f;
        #pragma unroll
        for (int e = 0; e < NE; e++) { ex[e] = expf(lg[e] - m); sum += ex[e]; }
        float inv = 1.0f / (sum + 1e-12f);
        int i0 = 0;
        #pragma unroll
        for (int e = 1; e < NE; e++) if (ex[e] > ex[i0]) i0 = e;
        int i1 = (i0 == 0) ? 1 : 0;
        #pragma unroll
        for (int e = 0; e < NE; e++) if (e != i0 && ex[e] > ex[i1]) i1 = e;
        slot_e[2 * tok]     = i0; slot_w[2 * tok]     = ex[i0] * inv;
        slot_e[2 * tok + 1] = i1; slot_w[2 * tok + 1] = ex[i1] * inv;
    }
}

// ------- Kernel 2: stable counting-sort routing: rank-within-expert + capacity drop -------
__global__ __launch_bounds__(1024) void route_build_kernel(
    const int* __restrict__ slot_e, const float* __restrict__ slot_w,
    int* __restrict__ row_token, float* __restrict__ row_w, int* __restrict__ n_rows)
{
    __shared__ int hist[1024][NE];
    int t = threadIdx.x;
    int cnt[NE];
    #pragma unroll
    for (int e = 0; e < NE; e++) cnt[e] = 0;
    int se[16];
    #pragma unroll
    for (int i = 0; i < 16; i++) { se[i] = slot_e[t * 16 + i]; cnt[se[i]]++; }
    #pragma unroll
    for (int e = 0; e < NE; e++) hist[t][e] = cnt[e];
    __syncthreads();
    for (int off = 1; off < 1024; off <<= 1) {
        int v[NE];
        bool has = (t >= off);
        if (has) {
            #pragma unroll
            for (int e = 0; e < NE; e++) v[e] = hist[t - off][e];
        }
        __syncthreads();
        if (has) {
            #pragma unroll
            for (int e = 0; e < NE; e++) hist[t][e] += v[e];
        }
        __syncthreads();
    }
    int run[NE];
    #pragma unroll
    for (int e = 0; e < NE; e++) run[e] = hist[t][e] - cnt[e];  // exclusive prefix
    if (t < NE) n_rows[t] = min(hist[1023][t], CAP);
    for (int i = 0; i < 16; i++) {
        int sidx = t * 16 + i;
        int e = se[i];
        int rnk = run[e]++;
        if (rnk < CAP) {
            int dest = e * CAP + rnk;
            row_token[dest] = sidx >> 1;
            row_w[dest] = slot_w[sidx];
        }
    }
}

// ------- Kernel 3: GEMM1 (gathered xn @ W12h^T), global_load_lds staging, fused SiLU*u -------
// block tile: 128 rows x (128 g-cols + 128 u-cols). XOR-swizzled LDS, unpadded 128B rows.
__global__ __launch_bounds__(256, 2) void gemm1_kernel(
    const _Float16* __restrict__ xn16, const _Float16* __restrict__ W12h,
    const int* __restrict__ n_rows, const int* __restrict__ row_token,
    _Float16* __restrict__ H)
{
    int e = blockIdx.z;
    int m0 = blockIdx.y * 128;
    int c0 = blockIdx.x * 128;
    int ne = n_rows[e];
    if (m0 >= ne) return;
    __shared__ _Float16 Al[128 * 64];
    __shared__ _Float16 Bl[256 * 64];
    int tid = threadIdx.x;
    int lane = tid & 63, wave = tid >> 6;
    int r = lane & 15, q = lane >> 4;
    int wm = (wave & 1) * 64, wn = (wave >> 1) * 64;

    // Precompute per-issue global base pointers (k-independent).
    // chunk ci = v*256 + tid; row = ci>>3; phys slot = ci&7; logical chunk = slot ^ (row&7)
    const _Float16* agp[4];
    #pragma unroll
    for (int v = 0; v < 4; v++) {
        int ci = v * 256 + tid;
        int row = ci >> 3, slot = ci & 7;
        int c = slot ^ (row & 7);
        int token = (m0 + row < ne) ? row_token[e * CAP + m0 + row] : 0;
        agp[v] = xn16 + (size_t)token * DM + c * 8;
    }
    const _Float16* bgp[8];
    const _Float16* Wb = W12h + (size_t)e * (2 * DFF) * DM;
    #pragma unroll
    for (int v = 0; v < 8; v++) {
        int ci = v * 256 + tid;
        int row = ci >> 3, slot = ci & 7;
        int c = slot ^ (row & 7);
        int frow = (row < 128) ? (c0 + row) : (DFF + c0 + row - 128);
        bgp[v] = Wb + (size_t)frow * DM + c * 8;
    }

    f32x4 accg[4][4] = {};
    f32x4 accu[4][4] = {};
    for (int k0 = 0; k0 < DM; k0 += 64) {
        #pragma unroll
        for (int v = 0; v < 4; v++)
            async16(agp[v] + k0, Al + v * 2048 + (tid >> 6) * 512);
        #pragma unroll
        for (int v = 0; v < 8; v++)
            async16(bgp[v] + k0, Bl + v * 2048 + (tid >> 6) * 512);
        __syncthreads();
        #pragma unroll
        for (int kf = 0; kf < 2; kf++) {
            f16x8 a[4], bg[4], bu[4];
            #pragma unroll
            for (int i = 0; i < 4; i++) {
                int R = wm + i * 16 + r;
                int pc = (kf * 4 + q) ^ (R & 7);
                a[i] = *(const f16x8*)(&Al[R * 64 + pc * 8]);
            }
            #pragma unroll
            for (int j = 0; j < 4; j++) {
                int Rg = wn + j * 16 + r;
                int pcg = (kf * 4 + q) ^ (Rg & 7);
                bg[j] = *(const f16x8*)(&Bl[Rg * 64 + pcg * 8]);
                int Ru = 128 + wn + j * 16 + r;
                int pcu = (kf * 4 + q) ^ (Ru & 7);
                bu[j] = *(const f16x8*)(&Bl[Ru * 64 + pcu * 8]);
            }
            #pragma unroll
            for (int i = 0; i < 4; i++) {
                #pragma unroll
                for (int j = 0; j < 4; j++) {
                    accg[i][j] = __builtin_amdgcn_mfma_f32_16x16x32_f16(a[i], bg[j], accg[i][j], 0, 0, 0);
                    accu[i][j] = __builtin_amdgcn_mfma_f32_16x16x32_f16(a[i], bu[j], accu[i][j], 0, 0, 0);
                }
            }
        }
        __syncthreads();
    }
    // epilogue: h = silu(g) * u, store fp16
    #pragma unroll
    for (int i = 0; i < 4; i++) {
        #pragma unroll
        for (int j = 0; j < 4; j++) {
            #pragma unroll
            for (int g = 0; g < 4; g++) {
                int row = wm + i * 16 + q * 4 + g;
                int col = wn + j * 16 + r;
                float gv = accg[i][j][g], uv = accu[i][j][g];
                float h = gv / (1.0f + __expf(-gv)) * uv;
                H[((size_t)(e * CAP + m0 + row)) * DFF + c0 + col] = (_Float16)h;
            }
        }
    }
}

// ------- Kernel 4: GEMM2 (H @ W3h^T), global_load_lds staging, fused atomic combine -------
__global__ __launch_bounds__(256, 2) void gemm2_kernel(
    const _Float16* __restrict__ H, const _Float16* __restrict__ W3h,
    const int* __restrict__ n_rows, const int* __restrict__ row_token,
    const float* __restrict__ row_w, float* __restrict__ out)
{
    int e = blockIdx.z;
    int m0 = blockIdx.y * 128;
    int c0 = blockIdx.x * 128;
    int ne = n_rows[e];
    if (m0 >= ne) return;
    __shared__ _Float16 Al[128 * 64];
    __shared__ _Float16 Bl[128 * 64];
    int tid = threadIdx.x;
    int lane = tid & 63, wave = tid >> 6;
    int r = lane & 15, q = lane >> 4;
    int wm = (wave & 1) * 64, wn = (wave >> 1) * 64;

    const _Float16* agp[4];
    const _Float16* Ab = H + ((size_t)(e * CAP + m0)) * DFF;
    #pragma unroll
    for (int v = 0; v < 4; v++) {
        int ci = v * 256 + tid;
        int row = ci >> 3, slot = ci & 7;
        int c = slot ^ (row & 7);
        agp[v] = Ab + (size_t)row * DFF + c * 8;
    }
    const _Float16* bgp[4];
    const _Float16* Wb = W3h + (size_t)e * DM * DFF;
    #pragma unroll
    for (int v = 0; v < 4; v++) {
        int ci = v * 256 + tid;
        int row = ci >> 3, slot = ci & 7;
        int c = slot ^ (row & 7);
        bgp[v] = Wb + (size_t)(c0 + row) * DFF + c * 8;
    }

    f32x4 acc[4][4] = {};
    for (int k0 = 0; k0 < DFF; k0 += 64) {
        #pragma unroll
        for (int v = 0; v < 4; v++)
            async16(agp[v] + k0, Al + v * 2048 + (tid >> 6) * 512);
        #pragma unroll
        for (int v = 0; v < 4; v++)
            async16(bgp[v] + k0, Bl + v * 2048 + (tid >> 6) * 512);
        __syncthreads();
        #pragma unroll
        for (int kf = 0; kf < 2; kf++) {
            f16x8 a[4], b[4];
            #pragma unroll
            for (int i = 0; i < 4; i++) {
                int R = wm + i * 16 + r;
                int pc = (kf * 4 + q) ^ (R & 7);
                a[i] = *(const f16x8*)(&Al[R * 64 + pc * 8]);
            }
            #pragma unroll
            for (int j = 0; j < 4; j++) {
                int R = wn + j * 16 + r;
                int pc = (kf * 4 + q) ^ (R & 7);
                b[j] = *(const f16x8*)(&Bl[R * 64 + pc * 8]);
            }
            #pragma unroll
            for (int i = 0; i < 4; i++) {
                #pragma unroll
                for (int j = 0; j < 4; j++)
                    acc[i][j] = __builtin_amdgcn_mfma_f32_16x16x32_f16(a[i], b[j], acc[i][j], 0, 0, 0);
            }
        }
        __syncthreads();
    }
    // epilogue: out[token] += w * y  (each out element touched by <= 2 slots)
    #pragma unroll
    for (int i = 0; i < 4; i++) {
        #pragma unroll
        for (int g = 0; g < 4; g++) {
            int m = m0 + wm + i * 16 + q * 4 + g;
            if (m < ne) {
                int dest = e * CAP + m;
                int tok = row_token[dest];
                float w = row_w[dest];
                #pragma unroll
                for (int j = 0; j < 4; j++) {
                    int col = c0 + wn + j * 16 + r;
                    atomicAdd(out + (size_t)tok * DM + col, w * acc[i][j][g]);
                }
            }
        }
    }
}

extern "C" void kernel_launch(void* const* d_in, const int* in_sizes, int n_in,
                              void* d_out, int out_size, void* d_ws, size_t ws_size,
                              hipStream_t stream) {
    const float* x     = (const float*)d_in[0];
    const float* gamma = (const float*)d_in[1];
    const float* beta  = (const float*)d_in[2];
    const float* Wr    = (const float*)d_in[3];
    const float* W12   = (const float*)d_in[4];
    const float* W3    = (const float*)d_in[5];
    float* out = (float*)d_out;
    char* ws = (char*)d_ws;

    _Float16* xn16    = (_Float16*)(ws);                 // 16,777,216 B
    _Float16* W12h    = (_Float16*)(ws + 16777216);      // 134,217,728 B
    _Float16* W3h     = (_Float16*)(ws + 150994944);     // 67,108,864 B
    _Float16* H       = (_Float16*)(ws + 218103808);     // 167,772,160 B
    int*      slot_e  = (int*)(ws + 385875968);          // 65,536 B
    float*    slot_w  = (float*)(ws + 385941504);        // 65,536 B
    int*      row_tok = (int*)(ws + 386007040);          // 81,920 B
    float*    row_w   = (float*)(ws + 386088960);        // 81,920 B
    int*      n_rows  = (int*)(ws + 386170880);          // 32 B

    hipMemsetAsync(d_out, 0, (size_t)out_size * sizeof(float), stream);

    hipLaunchKernelGGL(convert_kernel, dim3(4096), dim3(256), 0, stream,
                       W12, W12h, (NE * 2 * DFF * DM) / 4);
    hipLaunchKernelGGL(convert_kernel, dim3(2048), dim3(256), 0, stream,
                       W3, W3h, (NE * DM * DFF) / 4);
    hipLaunchKernelGGL(ln_router_kernel, dim3(T_TOKENS), dim3(256), 0, stream,
                       x, gamma, beta, Wr, xn16, slot_e, slot_w);
    hipLaunchKernelGGL(route_build_kernel, dim3(1), dim3(1024), 0, stream,
                       slot_e, slot_w, row_tok, row_w, n_rows);
    hipLaunchKernelGGL(gemm1_kernel, dim3(32, 20, NE), dim3(256), 0, stream,
                       xn16, W12h, n_rows, row_tok, H);
    hipLaunchKernelGGL(gemm2_kernel, dim3(8, 20, NE), dim3(256), 0, stream,
                       H, W3h, n_rows, row_tok, row_w, out);
}